// Round 5
// baseline (115.180 us; speedup 1.0000x reference)
//
#include <hip/hip_runtime.h>
#include <math.h>

#define T_STEPS 200
#define BB 512
#define DD 32
#define LMBD 1.0f
#define NCH 8          // t-chunks per b (one wave each)
#define CHT 25         // t per chunk

// ws layout (floats)
#define WS_MINV 0                  // sigma^{-T} [i][k], 1024
#define WS_A    1024               // A = sigma sigma^T, 1024
#define WS_W    2048               // weight[512]
#define WS_PART 2560               // per-b partials [512]
#define WS_DT   3072               // dt[200]
#define WS_SDT  3328               // sqrt(LMBD*dt)[200]
#define WS_CT   4096               // chunk c-totals [512][8][32]
#define WS_Y    135168             // chunk Y [512][8][32]
#define WS_M    266240             // chunk <A,M> scalars [512][8]

// ---------------------------------------------------------------------------
// Kernel 1: prep. weight = exp(lpd+lps+ltw); A = sigma sigma^T; dt/sdt tables;
// sigma^{-T} via single-wave register Gauss-Jordan (no pivoting; sigma ~ I).
// ---------------------------------------------------------------------------
__global__ __launch_bounds__(512) void prep_kernel(
    const float* __restrict__ ts,
    const float* __restrict__ sigma,
    const float* __restrict__ lpd, const float* __restrict__ lps,
    const float* __restrict__ ltw,
    float* __restrict__ ws)
{
    __shared__ float sg[32][33];
    const int tid = threadIdx.x;

    ws[WS_W + tid] = expf(lpd[tid] + lps[tid] + ltw[tid]);

    if (tid < T_STEPS) {
        float a = ts[tid], b = ts[tid + 1];
        float dt = b - a;
        ws[WS_DT + tid]  = dt;
        ws[WS_SDT + tid] = sqrtf(LMBD * dt);
    }

    for (int idx = tid; idx < 1024; idx += 512)
        sg[idx >> 5][idx & 31] = sigma[idx];
    __syncthreads();

    for (int idx = tid; idx < 1024; idx += 512) {
        int i = idx >> 5, j = idx & 31;
        float s = 0.0f;
        #pragma unroll
        for (int k = 0; k < 32; ++k) s += sg[i][k] * sg[j][k];
        ws[WS_A + idx] = s;
    }

    if (tid < 64) {
        const int l = tid;
        float col[32];
        #pragma unroll
        for (int r = 0; r < 32; ++r) {
            float v = sg[r][l & 31];
            col[r] = (l < 32) ? v : ((r == (l - 32)) ? 1.0f : 0.0f);
        }
        #pragma unroll
        for (int k = 0; k < 32; ++k) {
            float pinv = 1.0f / __shfl(col[k], k);
            col[k] *= pinv;
            #pragma unroll
            for (int r = 0; r < 32; ++r) {
                if (r == k) continue;
                float f = __shfl(col[r], k);
                col[r] -= f * col[k];
            }
        }
        if (l >= 32) {   // lane 32+c holds sigma^{-1} col c; Minv[i][k]=inv[k][i]
            #pragma unroll
            for (int r = 0; r < 32; ++r)
                ws[WS_MINV + (l - 32) * 32 + r] = col[r];
        }
    }
}

// ---------------------------------------------------------------------------
// Kernel 2 (stream): ONE WAVE per (chunk h, b). Barrier-free; all cross-lane
// via shuffles. Lane l = (j = l&31, half = l>>5).
// Per t: v = Minv*(-sdt*n - dt*ctl) [half-split bcast matvec];
//        y_j = P_j + V_j; pc via coalesced nb rowset dots + octet reduce;
//        P_j += dt*f_j + pc_j; M[rowset][colgrp] += y_r*y_c (16 regs).
// Chunk epilogue: m = <A,M>; write P (c-total), Y, m.
// ---------------------------------------------------------------------------
__global__ __launch_bounds__(64) void stream_kernel(
    const float* __restrict__ noises,
    const float* __restrict__ controls,
    const float* __restrict__ nabla_f,
    const float* __restrict__ nabla_V,
    const float* __restrict__ nabla_b,
    float* __restrict__ ws)
{
    const int h = blockIdx.x;          // 0..NCH-1
    const int b = blockIdx.y;          // 0..511
    const int l = threadIdx.x;         // 0..63
    const int j = l & 31;
    const int half = l >> 5;
    const int cg = l & 7;              // col group (4 cols)
    const int rg = l >> 3;             // row group: owns rows rg+8s, s=0..3

    const int t0 = h * CHT, t1 = t0 + CHT;

    // Minv half-row: Mv[c] = Minv[j][16*half + c]
    float Mv[16];
    #pragma unroll
    for (int c = 0; c < 16; ++c)
        Mv[c] = ws[WS_MINV + j * 32 + 16 * half + c];

    // per-half small-array pointers
    const float* sm1p = (half == 0) ? noises  : controls;
    const float* sm2p = (half == 0) ? nabla_f : nabla_V;

    const float4* nb = (const float4*)nabla_b;

    // prefetch t0
    size_t tf4 = (size_t)(t0 * BB + b) * 256;
    float4 n0 = nb[tf4 + l];
    float4 n1 = nb[tf4 + l + 64];
    float4 n2 = nb[tf4 + l + 128];
    float4 n3 = nb[tf4 + l + 192];
    float s1 = sm1p[(size_t)(t0 * BB + b) * DD + j];
    float s2 = sm2p[(size_t)(t0 * BB + b) * DD + j];

    float P = 0.0f, Yacc = 0.0f;
    float M00=0,M01=0,M02=0,M03=0, M10=0,M11=0,M12=0,M13=0;
    float M20=0,M21=0,M22=0,M23=0, M30=0,M31=0,M32=0,M33=0;

    for (int t = t0; t < t1; ++t) {
        // issue next-tile prefetch (clamped; no barriers -> stays in flight)
        const int tn = (t + 1 < t1) ? t + 1 : t;
        size_t tf4n = (size_t)(tn * BB + b) * 256;
        float4 m0 = nb[tf4n + l];
        float4 m1 = nb[tf4n + l + 64];
        float4 m2 = nb[tf4n + l + 128];
        float4 m3 = nb[tf4n + l + 192];
        float s1n = sm1p[(size_t)(tn * BB + b) * DD + j];
        float s2n = sm2p[(size_t)(tn * BB + b) * DD + j];

        const float dt  = ws[WS_DT + t];
        const float sdt = ws[WS_SDT + t];

        // exchange smalls across halves
        float o1 = __shfl_xor(s1, 32);
        float o2 = __shfl_xor(s2, 32);
        float nse = (half == 0) ? s1 : o1;
        float ctl = (half == 0) ? o1 : s1;
        float fv  = (half == 0) ? s2 : o2;
        float Vv  = (half == 0) ? o2 : s2;

        float w = -sdt * nse - dt * ctl;       // w_j (replicated both halves)

        // v matvec: partial over this half's 16 cols, then fold halves
        float part = 0.0f;
        #pragma unroll
        for (int c = 0; c < 16; ++c)
            part += Mv[c] * __shfl(w, 16 * half + c);
        float v = part + __shfl_xor(part, 32);  // v_j

        // y (uses P(t-1))
        float y = P + Vv;
        Yacc += y;

        // pc: lane owns rows {rg+8s}, cols 4cg..4cg+3
        float vg0 = __shfl(v, 4 * cg + 0);
        float vg1 = __shfl(v, 4 * cg + 1);
        float vg2 = __shfl(v, 4 * cg + 2);
        float vg3 = __shfl(v, 4 * cg + 3);
        float d0 = n0.x*vg0 + n0.y*vg1 + n0.z*vg2 + n0.w*vg3;
        float d1 = n1.x*vg0 + n1.y*vg1 + n1.z*vg2 + n1.w*vg3;
        float d2 = n2.x*vg0 + n2.y*vg1 + n2.z*vg2 + n2.w*vg3;
        float d3 = n3.x*vg0 + n3.y*vg1 + n3.z*vg2 + n3.w*vg3;
        // octet reduce (lanes sharing rg)
        d0 += __shfl_xor(d0,1); d0 += __shfl_xor(d0,2); d0 += __shfl_xor(d0,4);
        d1 += __shfl_xor(d1,1); d1 += __shfl_xor(d1,2); d1 += __shfl_xor(d1,4);
        d2 += __shfl_xor(d2,1); d2 += __shfl_xor(d2,2); d2 += __shfl_xor(d2,4);
        d3 += __shfl_xor(d3,1); d3 += __shfl_xor(d3,2); d3 += __shfl_xor(d3,4);
        // regather pc_j: src lane 8*(j&7), slot j>>3
        float g0 = __shfl(d0, 8 * (l & 7));
        float g1 = __shfl(d1, 8 * (l & 7));
        float g2 = __shfl(d2, 8 * (l & 7));
        float g3 = __shfl(d3, 8 * (l & 7));
        const int slot = (l >> 3) & 3;
        float pA = (slot & 1) ? g1 : g0;
        float pB = (slot & 1) ? g3 : g2;
        float pc = (slot & 2) ? pB : pA;

        P += dt * fv + pc;

        // M[rowset][colgrp] += y_r * y_c
        float yr0 = __shfl(y, rg + 0);
        float yr1 = __shfl(y, rg + 8);
        float yr2 = __shfl(y, rg + 16);
        float yr3 = __shfl(y, rg + 24);
        float yc0 = __shfl(y, 4 * cg + 0);
        float yc1 = __shfl(y, 4 * cg + 1);
        float yc2 = __shfl(y, 4 * cg + 2);
        float yc3 = __shfl(y, 4 * cg + 3);
        M00 += yr0*yc0; M01 += yr0*yc1; M02 += yr0*yc2; M03 += yr0*yc3;
        M10 += yr1*yc0; M11 += yr1*yc1; M12 += yr1*yc2; M13 += yr1*yc3;
        M20 += yr2*yc0; M21 += yr2*yc1; M22 += yr2*yc2; M23 += yr2*yc3;
        M30 += yr3*yc0; M31 += yr3*yc1; M32 += yr3*yc2; M33 += yr3*yc3;

        // rotate prefetch
        n0 = m0; n1 = m1; n2 = m2; n3 = m3; s1 = s1n; s2 = s2n;
    }

    // tail: t = 200 belongs to last chunk: y(200) = P + V(200)
    if (h == NCH - 1) {
        float Vt = nabla_V[((size_t)T_STEPS * BB + b) * DD + j];
        float y = P + Vt;
        Yacc += y;
        float yr0 = __shfl(y, rg + 0);
        float yr1 = __shfl(y, rg + 8);
        float yr2 = __shfl(y, rg + 16);
        float yr3 = __shfl(y, rg + 24);
        float yc0 = __shfl(y, 4 * cg + 0);
        float yc1 = __shfl(y, 4 * cg + 1);
        float yc2 = __shfl(y, 4 * cg + 2);
        float yc3 = __shfl(y, 4 * cg + 3);
        M00 += yr0*yc0; M01 += yr0*yc1; M02 += yr0*yc2; M03 += yr0*yc3;
        M10 += yr1*yc0; M11 += yr1*yc1; M12 += yr1*yc2; M13 += yr1*yc3;
        M20 += yr2*yc0; M21 += yr2*yc1; M22 += yr2*yc2; M23 += yr2*yc3;
        M30 += yr3*yc0; M31 += yr3*yc1; M32 += yr3*yc2; M33 += yr3*yc3;
    }

    // epilogue: m = <A, M>  (lane covers rows rg+8s x cols 4cg+k, each once)
    float mpart = 0.0f;
    {
        const float* Ab = ws + WS_A;
        float4 A0 = *(const float4*)(Ab + (rg +  0) * 32 + 4 * cg);
        float4 A1 = *(const float4*)(Ab + (rg +  8) * 32 + 4 * cg);
        float4 A2 = *(const float4*)(Ab + (rg + 16) * 32 + 4 * cg);
        float4 A3 = *(const float4*)(Ab + (rg + 24) * 32 + 4 * cg);
        mpart = M00*A0.x + M01*A0.y + M02*A0.z + M03*A0.w
              + M10*A1.x + M11*A1.y + M12*A1.z + M13*A1.w
              + M20*A2.x + M21*A2.y + M22*A2.z + M23*A2.w
              + M30*A3.x + M31*A3.y + M32*A3.z + M33*A3.w;
    }
    mpart += __shfl_xor(mpart, 1);
    mpart += __shfl_xor(mpart, 2);
    mpart += __shfl_xor(mpart, 4);
    mpart += __shfl_xor(mpart, 8);
    mpart += __shfl_xor(mpart, 16);
    mpart += __shfl_xor(mpart, 32);

    if (half == 0) {
        ws[WS_CT + (b * NCH + h) * 32 + j] = P;
        ws[WS_Y  + (b * NCH + h) * 32 + j] = Yacc;
    }
    if (l == 0) ws[WS_M + b * NCH + h] = mpart;
}

// ---------------------------------------------------------------------------
// Kernel 3 (combine): per b, resolve cross-chunk prefix algebra:
//   S = g + sum_h CT_h ; C_h = prefix ; S'_h = S - C_h
//   loss_b = w_b * sum_h [ n_h S'^T A S' - 2 S'^T A Y_h + m_h ]
// ---------------------------------------------------------------------------
__global__ __launch_bounds__(256) void combine_kernel(
    const float* __restrict__ nabla_g,
    float* __restrict__ ws)
{
    __shared__ float ct[NCH][32], Yl[NCH][32];
    __shared__ float Sv[32], Cp[32];
    __shared__ __align__(16) float sp[32];
    __shared__ float red[32];

    const int b   = blockIdx.x;
    const int tid = threadIdx.x;
    const int r   = tid >> 3;
    const int q   = tid & 7;

    {
        int hh = tid >> 5, i = tid & 31;   // 256 threads = 8x32 exactly
        ct[hh][i] = ws[WS_CT + (b * NCH + hh) * 32 + i];
        Yl[hh][i] = ws[WS_Y  + (b * NCH + hh) * 32 + i];
    }
    if (tid < 32) Cp[tid] = 0.0f;
    __syncthreads();
    if (tid < 32) {
        float s = nabla_g[b * 32 + tid];
        #pragma unroll
        for (int hh = 0; hh < NCH; ++hh) s += ct[hh][tid];
        Sv[tid] = s;
    }

    float acc = 0.0f;
    float4 A4 = *(const float4*)(ws + WS_A + r * 32 + 4 * q);
    for (int hh = 0; hh < NCH; ++hh) {
        __syncthreads();
        if (tid < 32) sp[tid] = Sv[tid] - Cp[tid];
        __syncthreads();
        float4 s4 = *(const float4*)&sp[4 * q];
        float as = A4.x * s4.x + A4.y * s4.y + A4.z * s4.z + A4.w * s4.w;
        as += __shfl_xor(as, 1);
        as += __shfl_xor(as, 2);
        as += __shfl_xor(as, 4);
        float nh = (hh == NCH - 1) ? (float)(CHT + 1) : (float)CHT;
        if (q == 0) acc += as * (nh * sp[r] - 2.0f * Yl[hh][r]);
        if (tid < 32) Cp[tid] += ct[hh][tid];
    }
    __syncthreads();
    if (q == 0) red[r] = acc;
    __syncthreads();
    if (tid == 0) {
        float s = 0.0f;
        #pragma unroll
        for (int i = 0; i < 32; ++i) s += red[i];
        #pragma unroll
        for (int hh = 0; hh < NCH; ++hh) s += ws[WS_M + b * NCH + hh];
        ws[WS_PART + b] = ws[WS_W + b] * s;
    }
}

// ---------------------------------------------------------------------------
// Kernel 4: deterministic final reduction
// ---------------------------------------------------------------------------
__global__ __launch_bounds__(512) void reduce_kernel(
    const float* __restrict__ ws, float* __restrict__ out)
{
    __shared__ float r[512];
    const int tid = threadIdx.x;
    r[tid] = ws[WS_PART + tid];
    __syncthreads();
    for (int st = 256; st > 0; st >>= 1) {
        if (tid < st) r[tid] += r[tid + st];
        __syncthreads();
    }
    if (tid == 0) out[0] = r[0] * (1.0f / (201.0f * 512.0f));
}

extern "C" void kernel_launch(void* const* d_in, const int* in_sizes, int n_in,
                              void* d_out, int out_size, void* d_ws, size_t ws_size,
                              hipStream_t stream) {
    (void)in_sizes; (void)n_in; (void)out_size; (void)ws_size;
    const float* ts       = (const float*)d_in[0];
    const float* noises   = (const float*)d_in[2];
    const float* controls = (const float*)d_in[3];
    const float* nabla_V  = (const float*)d_in[4];
    const float* nabla_f  = (const float*)d_in[5];
    const float* nabla_b  = (const float*)d_in[6];
    const float* nabla_g  = (const float*)d_in[7];
    const float* sigma    = (const float*)d_in[8];
    const float* lpd      = (const float*)d_in[9];
    const float* lps      = (const float*)d_in[10];
    const float* ltw      = (const float*)d_in[11];
    float* ws  = (float*)d_ws;
    float* out = (float*)d_out;

    prep_kernel<<<1, 512, 0, stream>>>(ts, sigma, lpd, lps, ltw, ws);
    stream_kernel<<<dim3(NCH, BB), 64, 0, stream>>>(noises, controls, nabla_f,
                                                    nabla_V, nabla_b, ws);
    combine_kernel<<<BB, 256, 0, stream>>>(nabla_g, ws);
    reduce_kernel<<<1, 512, 0, stream>>>(ws, out);
}